// Round 4
// baseline (1862.156 us; speedup 1.0000x reference)
//
#include <hip/hip_runtime.h>
#include <cstdint>
#include <cstddef>

// Problem constants (fixed by reference setup_inputs)
#define NQ     256      // queries
#define DEMB   768      // embedding dim
#define NTRAIN 200000   // train rows
#define SSAMP  4096     // sample rows for threshold estimation
#define RRANK  12       // sample rank -> threshold (expected ~585 global cands/query)
#define CAP    2048     // candidate cap per query
#define TOPK   32       // max_k
#define NC     64       // rows per block in dist kernel
#define KT     32       // k-chunk

// ---------------------------------------------------------------------------
// Kernel 1: transpose Q -> Qt[k][q], compute q2[q] = ||q||^2, zero counters.
// ---------------------------------------------------------------------------
__global__ __launch_bounds__(256) void qprep_kernel(const float* __restrict__ Q,
                                                    float* __restrict__ Qt,
                                                    float* __restrict__ q2,
                                                    int* __restrict__ cnt) {
  __shared__ float red[256];
  int q = blockIdx.x, tid = threadIdx.x;
  if (q == 0) cnt[tid] = 0;
  float s = 0.f;
  #pragma unroll
  for (int j = 0; j < 3; ++j) {
    int k = tid + j * 256;
    float v = Q[q * DEMB + k];
    Qt[k * NQ + q] = v;
    s = fmaf(v, v, s);
  }
  red[tid] = s;
  __syncthreads();
  for (int st = 128; st > 0; st >>= 1) {
    if (tid < st) red[tid] += red[tid + st];
    __syncthreads();
  }
  if (tid == 0) q2[q] = red[0];
}

// ---------------------------------------------------------------------------
// Kernel 2/4: tiled fp32 distance GEMM. Block: all 256 queries x 64 rows.
// MODE 0: write raw d2 to sample matrix. MODE 1: filter d2 < T[q], append.
// x2 (row norms) computed on the fly during B staging.
// B tile stored k-major (Btk[k][row]) so the inner-loop b-fragment is two
// ds_read_b128 broadcasts instead of eight ds_read_b32.
// ---------------------------------------------------------------------------
template <int MODE>
__global__ __launch_bounds__(256) void dist_kernel(
    const float* __restrict__ Qt, const float* __restrict__ X,
    const float* __restrict__ q2g, const float* __restrict__ Tg,
    float* __restrict__ samp, int* __restrict__ cnt, float2* __restrict__ cand) {
  __shared__ float A[KT][NQ];    // 32 KB, k-major query tile
  __shared__ float Btk[KT][NC];  // 8 KB, k-major X tile
  __shared__ float x2s[NC];

  const int tid = threadIdx.x;
  const int tq = tid & 31;  // query group: queries tq*8..tq*8+7
  const int tn = tid >> 5;  // row group:   rows    tn*8..tn*8+7
  const int n0 = blockIdx.x * NC;

  float acc[8][8];
  #pragma unroll
  for (int i = 0; i < 8; ++i)
    #pragma unroll
    for (int j = 0; j < 8; ++j) acc[i][j] = 0.f;
  if (tid < NC) x2s[tid] = 0.f;

  for (int k0 = 0; k0 < DEMB; k0 += KT) {
    // stage A: 32k x 256q floats, coalesced from Qt
    #pragma unroll
    for (int j = 0; j < 8; ++j) {
      int idx = tid + 256 * j;
      int kk = idx >> 6, q4 = idx & 63;
      float4 v = *(const float4*)(Qt + (size_t)(k0 + kk) * NQ + q4 * 4);
      *(float4*)(&A[kk][q4 * 4]) = v;
    }
    // stage B: 64 rows x 32 k floats, coalesced from X, transposed into Btk
    float4 bv[2];
    #pragma unroll
    for (int j = 0; j < 2; ++j) {
      int idx = tid + 256 * j;
      int r = idx >> 3, kc = idx & 7;
      float4 v = *(const float4*)(X + (size_t)(n0 + r) * DEMB + k0 + kc * 4);
      bv[j] = v;
      Btk[kc * 4 + 0][r] = v.x;
      Btk[kc * 4 + 1][r] = v.y;
      Btk[kc * 4 + 2][r] = v.z;
      Btk[kc * 4 + 3][r] = v.w;
    }
    __syncthreads();
    // accumulate row norms: reduce squares over the 8 kc-lanes of each row
    #pragma unroll
    for (int j = 0; j < 2; ++j) {
      int idx = tid + 256 * j;
      int r = idx >> 3, kc = idx & 7;
      float s = bv[j].x * bv[j].x + bv[j].y * bv[j].y + bv[j].z * bv[j].z + bv[j].w * bv[j].w;
      s += __shfl_xor(s, 1);
      s += __shfl_xor(s, 2);
      s += __shfl_xor(s, 4);
      if (kc == 0) x2s[r] += s;  // unique owner thread per row; read after loop-end barrier
    }
    // inner product: 8q x 8r register tile
    #pragma unroll 4
    for (int kk = 0; kk < KT; ++kk) {
      float a[8], b[8];
      *(float4*)(a)     = *(const float4*)(&A[kk][tq * 8]);
      *(float4*)(a + 4) = *(const float4*)(&A[kk][tq * 8 + 4]);
      *(float4*)(b)     = *(const float4*)(&Btk[kk][tn * 8]);
      *(float4*)(b + 4) = *(const float4*)(&Btk[kk][tn * 8 + 4]);
      #pragma unroll
      for (int i = 0; i < 8; ++i)
        #pragma unroll
        for (int j = 0; j < 8; ++j)
          acc[i][j] = fmaf(a[i], b[j], acc[i][j]);
    }
    __syncthreads();
  }

  float x2r[8], q2r[8], Tr[8];
  #pragma unroll
  for (int j = 0; j < 8; ++j) x2r[j] = x2s[tn * 8 + j];
  #pragma unroll
  for (int i = 0; i < 8; ++i) q2r[i] = q2g[tq * 8 + i];
  if (MODE == 1) {
    #pragma unroll
    for (int i = 0; i < 8; ++i) Tr[i] = Tg[tq * 8 + i];
  }
  #pragma unroll
  for (int i = 0; i < 8; ++i) {
    int q = tq * 8 + i;
    #pragma unroll
    for (int j = 0; j < 8; ++j) {
      int n = n0 + tn * 8 + j;
      float d2 = fmaf(-2.f, acc[i][j], q2r[i] + x2r[j]);
      if (MODE == 0) {
        samp[q * SSAMP + n] = d2;
      } else {
        if (d2 < Tr[i]) {
          int pos = atomicAdd(&cnt[q], 1);
          if (pos < CAP) cand[(size_t)q * CAP + pos] = make_float2(d2, __int_as_float(n));
        }
      }
    }
  }
}

// ---------------------------------------------------------------------------
// Kernel 3: per-query threshold = RRANK-th smallest of the sample row,
// found by bisection on count(< mid) over the LDS-resident sample.
// ---------------------------------------------------------------------------
__global__ __launch_bounds__(256) void thresh_kernel(const float* __restrict__ samp,
                                                     float* __restrict__ T) {
  __shared__ float v[SSAMP];
  __shared__ float rlo[256], rhi[256];
  __shared__ int csh;
  int q = blockIdx.x, tid = threadIdx.x;
  float lo = 3.4e38f, hi = -3.4e38f;
  for (int i = tid; i < SSAMP; i += 256) {
    float x = samp[q * SSAMP + i];
    v[i] = x;
    lo = fminf(lo, x);
    hi = fmaxf(hi, x);
  }
  rlo[tid] = lo; rhi[tid] = hi;
  __syncthreads();
  for (int st = 128; st > 0; st >>= 1) {
    if (tid < st) {
      rlo[tid] = fminf(rlo[tid], rlo[tid + st]);
      rhi[tid] = fmaxf(rhi[tid], rhi[tid + st]);
    }
    __syncthreads();
  }
  lo = rlo[0];
  hi = rhi[0] + 1.0f;  // invariant: count(< hi) >= RRANK
  for (int it = 0; it < 40; ++it) {
    float mid = 0.5f * (lo + hi);
    int c = 0;
    for (int i = tid; i < SSAMP; i += 256) c += (v[i] < mid) ? 1 : 0;
    if (tid == 0) csh = 0;
    __syncthreads();
    atomicAdd(&csh, c);
    __syncthreads();
    if (csh >= RRANK) hi = mid; else lo = mid;
    __syncthreads();
  }
  if (tid == 0) T[q] = hi;
}

// ---------------------------------------------------------------------------
// Kernel 5: per-query exact top-32 (ascending d2, index tie-break = top_k
// semantics) from the candidate list, then the linear layer + cumulative
// softmax-weighted prefix scores.
// ---------------------------------------------------------------------------
__global__ __launch_bounds__(256) void final_kernel(
    const float2* __restrict__ cand, const int* __restrict__ cnt,
    const float* __restrict__ Y, const int* __restrict__ sysT,
    const int* __restrict__ qsys, const float* __restrict__ W,
    const float* __restrict__ bb, float* __restrict__ out) {
  __shared__ float d_l[CAP];
  __shared__ int i_l[CAP];
  __shared__ float bd[256];
  __shared__ int bi[256];
  __shared__ int bp[256];
  __shared__ float seld[TOPK];
  __shared__ int seli[TOPK];
  __shared__ float ndv[TOPK], sv[TOPK];
  int q = blockIdx.x, tid = threadIdx.x;
  int n = cnt[q];
  if (n > CAP) n = CAP;
  for (int i = tid; i < CAP; i += 256) {
    if (i < n) {
      float2 c = cand[(size_t)q * CAP + i];
      d_l[i] = c.x;
      i_l[i] = __float_as_int(c.y);
    } else {
      d_l[i] = 3.4e38f;
      i_l[i] = 0x7fffffff;
    }
  }
  __syncthreads();
  for (int r = 0; r < TOPK; ++r) {
    float best = 3.4e38f; int bidx = 0x7fffffff; int bpos = 0;
    for (int i = tid; i < CAP; i += 256) {
      float d = d_l[i]; int ix = i_l[i];
      if (d < best || (d == best && ix < bidx)) { best = d; bidx = ix; bpos = i; }
    }
    bd[tid] = best; bi[tid] = bidx; bp[tid] = bpos;
    __syncthreads();
    for (int st = 128; st > 0; st >>= 1) {
      if (tid < st) {
        float dd = bd[tid + st]; int ii = bi[tid + st];
        if (dd < bd[tid] || (dd == bd[tid] && ii < bi[tid])) {
          bd[tid] = dd; bi[tid] = ii; bp[tid] = bp[tid + st];
        }
      }
      __syncthreads();
    }
    if (tid == 0) {
      seld[r] = bd[0];
      seli[r] = bi[0];
      d_l[bp[0]] = 3.4e38f;
      i_l[bp[0]] = 0x7fffffff;
    }
    __syncthreads();
  }
  if (tid < TOPK) {
    int idx = seli[tid];
    if ((unsigned)idx >= (unsigned)NTRAIN) idx = 0;  // safety: impossible unless <32 cands
    float d = seld[tid];
    float y = Y[idx];
    int s = sysT[idx];
    float w0 = W[0], w1 = W[1], b0 = bb[0], b1 = bb[1];
    float nd = (s == qsys[q]) ? fmaf(d, w1, b1) : fmaf(d, w0, b0);
    ndv[tid] = nd;
    sv[tid] = y;
    out[q * TOPK + tid] = nd;
  }
  __syncthreads();
  if (tid == 0) {
    float m = -3.4e38f;
    for (int j = 0; j < TOPK; ++j) m = fmaxf(m, -ndv[j]);
    float num = 0.f, den = 0.f;
    for (int j = 0; j < TOPK; ++j) {
      float w = expf(-ndv[j] - m);
      num = fmaf(w, sv[j], num);
      den += w;
      out[NQ * TOPK + q * TOPK + j] = num / den;
    }
  }
}

// ---------------------------------------------------------------------------
extern "C" void kernel_launch(void* const* d_in, const int* in_sizes, int n_in,
                              void* d_out, int out_size, void* d_ws, size_t ws_size,
                              hipStream_t stream) {
  const float* Q    = (const float*)d_in[0];
  const int*   qsys = (const int*)d_in[1];
  const float* X    = (const float*)d_in[2];
  const float* Y    = (const float*)d_in[3];
  const int*   sysT = (const int*)d_in[4];
  const float* W    = (const float*)d_in[5];
  const float* bb   = (const float*)d_in[6];
  float* out = (float*)d_out;
  char* ws = (char*)d_ws;

  // workspace layout (total ~8.76 MB)
  float*  Qt   = (float*)(ws);                 // 768*256*4 = 786432
  float*  q2   = (float*)(ws + 786432);        // 1024
  float*  T    = (float*)(ws + 787456);        // 1024
  int*    cnt  = (int*)(ws + 788480);          // 1024
  float*  samp = (float*)(ws + 789504);        // 256*4096*4 = 4194304
  float2* cand = (float2*)(ws + 4983808);      // 256*2048*8 = 4194304

  hipLaunchKernelGGL(qprep_kernel, dim3(NQ), dim3(256), 0, stream, Q, Qt, q2, cnt);
  hipLaunchKernelGGL((dist_kernel<0>), dim3(SSAMP / NC), dim3(256), 0, stream,
                     Qt, X, q2, T, samp, cnt, cand);
  hipLaunchKernelGGL(thresh_kernel, dim3(NQ), dim3(256), 0, stream, samp, T);
  hipLaunchKernelGGL((dist_kernel<1>), dim3(NTRAIN / NC), dim3(256), 0, stream,
                     Qt, X, q2, T, samp, cnt, cand);
  hipLaunchKernelGGL(final_kernel, dim3(NQ), dim3(256), 0, stream,
                     cand, cnt, Y, sysT, qsys, W, bb, out);
}